// Round 4
// baseline (276.879 us; speedup 1.0000x reference)
//
#include <hip/hip_runtime.h>
#include <cstdint>
#include <cstddef>

// Fused transformer block: out = LN(FFN(LN(attn(x)+x)) + LN(attn(x)+x))
// Z=64, N=2048, D=64, DFF=32, causal, single head.
// Kernels: proj (QKV -> ws), fused (attn + LN + FFN + LN -> out).
// ws layout: Qb bf16 | Kb bf16 | Vt bf16 [Z][D][N]  (~50 MB)

#define ZB   64
#define NCTX 2048
#define DH   64
#define DFF  32
// base-2 softmax: score*SM_SCALE*log2(e); mask -1e9 pre-scale -> NEGS2 in log2 domain
#define SC2   0.18033688011112042f
#define NEGS2 (-1.8033688e8f)

typedef float f32x4  __attribute__((ext_vector_type(4)));
typedef float f32x16 __attribute__((ext_vector_type(16)));
typedef __bf16 bf16x8 __attribute__((ext_vector_type(8)));
typedef unsigned int u32x4 __attribute__((ext_vector_type(4)));

#define MFMA32(a, b, c) __builtin_amdgcn_mfma_f32_32x32x16_bf16((a), (b), (c), 0, 0, 0)

static __device__ __forceinline__ unsigned cvtpk_bf16(float a, float b) {
  unsigned r;
  asm("v_cvt_pk_bf16_f32 %0, %1, %2" : "=v"(r) : "v"(a), "v"(b));
  return r;
}
static __device__ __forceinline__ void plswap32(unsigned &a, unsigned &b) {
  asm volatile("v_permlane32_swap_b32 %0, %1" : "+v"(a), "+v"(b));
}
static __device__ __forceinline__ float exp2a(float x) {
  float r;
  asm("v_exp_f32 %0, %1" : "=v"(r) : "v"(x));
  return r;
}
// build a bf16x8 frag ordered {own-half, partner-half} by hi from 8 f32 regs
static __device__ __forceinline__ bf16x8 pack_frag(
    float v0, float v1, float v2, float v3,
    float v4, float v5, float v6, float v7) {
  unsigned A0 = cvtpk_bf16(v0, v1), A1 = cvtpk_bf16(v2, v3);
  unsigned B0 = cvtpk_bf16(v4, v5), B1 = cvtpk_bf16(v6, v7);
  plswap32(A0, B0); plswap32(A1, B1);
  u32x4 u = {A0, A1, B0, B1};
  return __builtin_bit_cast(bf16x8, u);
}

// ---------------------------------------------------------------------------
// Kernel 1: QKV projection. grid = Z*N/64 blocks, 192 threads (3 waves).
// Wave w computes matrix w (Q/K/V) for 64 rows; weights live in 64 VGPRs/lane.
// V is written transposed [b][d][n] via an LDS transpose tile.
// ---------------------------------------------------------------------------
__global__ __launch_bounds__(192) void proj_kernel(
    const float* __restrict__ x, const float* __restrict__ wq,
    const float* __restrict__ wk, const float* __restrict__ wv,
    __bf16* __restrict__ Qb, __bf16* __restrict__ Kb, __bf16* __restrict__ Vt)
{
  const int b  = blockIdx.x >> 5;           // N/64 = 32 tiles per batch
  const int n0 = (blockIdx.x & 31) << 6;
  const int w  = threadIdx.x >> 6;
  const int l  = threadIdx.x & 63;

  __shared__ __bf16 vtile[64][66];          // padded: conflict-free transpose read

  const float* wsel = (w == 0) ? wq : (w == 1) ? wk : wv;
  float wreg[64];
  #pragma unroll
  for (int d = 0; d < 64; ++d) wreg[d] = wsel[d * 64 + l];  // column l of weight

  const size_t rb0 = ((size_t)b * NCTX + n0) * DH;
  for (int n = 0; n < 64; ++n) {
    const float* xr = x + rb0 + (size_t)n * DH;   // wave-uniform address
    float acc = 0.f;
    #pragma unroll
    for (int d = 0; d < 64; ++d) acc += xr[d] * wreg[d];
    if (w == 0)      Qb[rb0 + n * DH + l] = (__bf16)acc;
    else if (w == 1) Kb[rb0 + n * DH + l] = (__bf16)acc;
    else             vtile[n][l] = (__bf16)acc;
  }
  if (w == 2) {
    asm volatile("s_waitcnt lgkmcnt(0)" ::: "memory");
    __builtin_amdgcn_sched_barrier(0);
    #pragma unroll 8
    for (int d = 0; d < 64; ++d)
      Vt[((size_t)b * 64 + d) * NCTX + n0 + l] = vtile[l][d];
  }
}

// ---------------------------------------------------------------------------
// Kernel 2: fused causal flash attention + LN + FFN + LN.
// grid = Z*32 blocks x 128 threads (2 waves). Wave 0 -> q-tile tp, wave 1 ->
// q-tile 63-tp (balanced: every block = 65 kv-tile iterations). No LDS.
// Attn: S^T = mfma32(K,Q), in-register base-2 online softmax (lane owns q-row
// l&31, partner l^32 holds other half), O^T = mfma32(V^T, P^T), defer-max.
// Epilogue (per wave, in-register): y = LN(O+x) via in-lane sum + shfl(32);
// y -> bf16 frags via cvt_pk+permlane32_swap; h^T = relu(mfma32(w1^T, y));
// ff^T = mfma32(w2^T, h^T); out = LN(ff + y). Zero LDS, no intermediate HBM.
// ---------------------------------------------------------------------------
__global__ __launch_bounds__(128) void fused_kernel(
    const __bf16* __restrict__ Qb, const __bf16* __restrict__ Kb,
    const __bf16* __restrict__ Vt, const float* __restrict__ kpm,
    const float* __restrict__ x,  const float* __restrict__ w1,
    const float* __restrict__ w2, float* __restrict__ out)
{
  const int bid = (blockIdx.x & 7) * 256 + (blockIdx.x >> 3);  // XCD chunking
  const int b   = bid >> 5;
  const int tp  = bid & 31;
  const int wv  = threadIdx.x >> 6;
  const int l   = threadIdx.x & 63;
  const int q5  = l & 31;
  const int hi  = l >> 5;
  const int t   = wv ? (63 - tp) : tp;
  const int qw  = t << 5;
  const int n   = qw + q5;                  // this lane's q row

  // Q fragments: lane supplies Q[n][16c + 8hi + i]  (B-operand, col = q)
  const __bf16* qp = Qb + ((size_t)(b * NCTX + n)) * DH + hi * 8;
  bf16x8 qf[4];
  #pragma unroll
  for (int c = 0; c < 4; ++c) qf[c] = *(const bf16x8*)(qp + 16 * c);

  f32x16 acc[2];
  #pragma unroll
  for (int r = 0; r < 16; ++r) { acc[0][r] = 0.f; acc[1][r] = 0.f; }
  float m_run = -1e30f, ls = 0.f;

  const float*  kpb   = kpm + b * NCTX;
  const __bf16* kbase = Kb + ((size_t)b * NCTX + q5) * DH + hi * 8;
  const __bf16* vbase = Vt + ((size_t)(b * DH + q5)) * NCTX + hi * 8;

  for (int kv0 = 0; kv0 <= qw; kv0 += 32) {
    const bool diag = (kv0 == qw);          // wave-uniform

    // S^T = K_tile . Q^T : 4 MFMAs over D=64
    const __bf16* kp = kbase + (size_t)kv0 * DH;
    f32x16 s;
    #pragma unroll
    for (int r = 0; r < 16; ++r) s[r] = 0.f;
    #pragma unroll
    for (int c = 0; c < 4; ++c) {
      const bf16x8 kf = *(const bf16x8*)(kp + (size_t)16 * c);
      s = MFMA32(kf, qf[c], s);
    }

    // V B-frags issued EARLY (addresses independent of s) to hide latency
    const __bf16* vp = vbase + kv0;
    const bf16x8 vf0 = *(const bf16x8*)(vp);
    const bf16x8 vf1 = *(const bf16x8*)(vp + 16);
    const bf16x8 vf2 = *(const bf16x8*)(vp + (size_t)32 * NCTX);
    const bf16x8 vf3 = *(const bf16x8*)(vp + (size_t)32 * NCTX + 16);

    // key-padding-mask values for this lane's 16 kv slots (reg r -> kv rm(r))
    f32x4 kb[4];
    #pragma unroll
    for (int g = 0; g < 4; ++g)
      kb[g] = *(const f32x4*)(kpb + kv0 + 4 * hi + 8 * g);

    float p[16];
    #pragma unroll
    for (int r = 0; r < 16; ++r) {
      float tv = (s[r] + kb[r >> 2][r & 3]) * SC2;
      if (diag) {
        const int rm = (r & 3) + 8 * (r >> 2) + 4 * hi;   // kv offset in tile
        tv = (rm > q5) ? tv + NEGS2 : tv;                 // causal: j > i
      }
      p[r] = tv;
    }

    // row max: in-lane tree + partner exchange
    float m0 = fmaxf(fmaxf(p[0], p[1]),  fmaxf(p[2], p[3]));
    float m1 = fmaxf(fmaxf(p[4], p[5]),  fmaxf(p[6], p[7]));
    float m2 = fmaxf(fmaxf(p[8], p[9]),  fmaxf(p[10], p[11]));
    float m3 = fmaxf(fmaxf(p[12], p[13]), fmaxf(p[14], p[15]));
    float mx = fmaxf(fmaxf(m0, m1), fmaxf(m2, m3));
    mx = fmaxf(mx, __shfl_xor(mx, 32));

    if (!__all(mx <= m_run + 11.0f)) {      // defer-max (T13)
      const float mn = fmaxf(m_run, mx);
      const float sc = exp2a(m_run - mn);   // first iter: exp2(-1e30)=0
      m_run = mn;
      ls *= sc;
      #pragma unroll
      for (int r = 0; r < 16; ++r) { acc[0][r] *= sc; acc[1][r] *= sc; }
    }

    #pragma unroll
    for (int r = 0; r < 16; ++r) p[r] = exp2a(p[r] - m_run);
    float t0 = (p[0] + p[1])  + (p[2] + p[3]);
    float t1 = (p[4] + p[5])  + (p[6] + p[7]);
    float t2 = (p[8] + p[9])  + (p[10] + p[11]);
    float t3 = (p[12] + p[13]) + (p[14] + p[15]);
    float rs = (t0 + t1) + (t2 + t3);
    rs += __shfl_xor(rs, 32);
    ls += rs;

    // P^T -> bf16 B-frags (kv 0..15 and 16..31) via cvt_pk + permlane32_swap
    const bf16x8 pf0 = pack_frag(p[0], p[1], p[2],  p[3],  p[4],  p[5],  p[6],  p[7]);
    const bf16x8 pf1 = pack_frag(p[8], p[9], p[10], p[11], p[12], p[13], p[14], p[15]);

    // O^T += V^T . P^T : A-frag = Vt rows (d), 2 d-blocks x 2 kv-halves
    acc[0] = MFMA32(vf0, pf0, acc[0]);
    acc[0] = MFMA32(vf1, pf1, acc[0]);
    acc[1] = MFMA32(vf2, pf0, acc[1]);
    acc[1] = MFMA32(vf3, pf1, acc[1]);
  }

  // ------------------ fused epilogue: LN1 + FFN + LN2 ------------------
  // lane layout: value (db, r) lives at d = 32db + 8(r>>2) + 4hi + (r&3);
  // partner lane (l^32) holds the other 4-offsets -> row ops = in-lane + shfl(32).
  const float invl = 1.f / ls;
  const float* xrow = x + ((size_t)(b * NCTX + n)) * DH;

  // residual1: t = O + x ; LN over d=64
  float y[2][16];
  float s1 = 0.f, s2 = 0.f;
  #pragma unroll
  for (int db = 0; db < 2; ++db)
    #pragma unroll
    for (int g = 0; g < 4; ++g) {
      const f32x4 xv = *(const f32x4*)(xrow + 32 * db + 8 * g + 4 * hi);
      #pragma unroll
      for (int j = 0; j < 4; ++j) {
        const float tv = acc[db][4 * g + j] * invl + xv[j];
        y[db][4 * g + j] = tv;
        s1 += tv; s2 += tv * tv;
      }
    }
  s1 += __shfl_xor(s1, 32);
  s2 += __shfl_xor(s2, 32);
  {
    const float mu   = s1 * (1.f / 64.f);
    const float var  = s2 * (1.f / 64.f) - mu * mu;
    const float rstd = rsqrtf(var + 1e-5f);
    #pragma unroll
    for (int db = 0; db < 2; ++db)
      #pragma unroll
      for (int r = 0; r < 16; ++r) y[db][r] = (y[db][r] - mu) * rstd;
  }

  // y -> bf16 frags: yb[kk] supplies [row n][k = 16kk + 8hi + i]
  bf16x8 yb[4];
  #pragma unroll
  for (int kk = 0; kk < 4; ++kk) {
    const int db = kk >> 1, rb = 8 * (kk & 1);
    yb[kk] = pack_frag(y[db][rb + 0], y[db][rb + 1], y[db][rb + 2], y[db][rb + 3],
                       y[db][rb + 4], y[db][rb + 5], y[db][rb + 6], y[db][rb + 7]);
  }

  // w1^T A-frags: A[f = q5][k = d] = w1[d*DFF + f]
  f32x16 hc;
  #pragma unroll
  for (int r = 0; r < 16; ++r) hc[r] = 0.f;
  #pragma unroll
  for (int kk = 0; kk < 4; ++kk) {
    bf16x8 aw;
    #pragma unroll
    for (int i = 0; i < 8; ++i)
      aw[i] = (__bf16)w1[(16 * kk + 8 * hi + i) * DFF + q5];
    hc = MFMA32(aw, yb[kk], hc);
  }
  // h^T: lane owns col q (= n), rows f = 8(r>>2)+4hi+(r&3); relu
  float hv[16];
  #pragma unroll
  for (int r = 0; r < 16; ++r) hv[r] = fmaxf(hc[r], 0.f);

  // h -> bf16 frags (k = f): hb[kk2] supplies [col n][k = 16kk2 + 8hi + i]
  bf16x8 hb[2];
  #pragma unroll
  for (int kk2 = 0; kk2 < 2; ++kk2) {
    const int rb = 8 * kk2;
    hb[kk2] = pack_frag(hv[rb + 0], hv[rb + 1], hv[rb + 2], hv[rb + 3],
                        hv[rb + 4], hv[rb + 5], hv[rb + 6], hv[rb + 7]);
  }

  // ff^T = w2^T . h^T : A[d = 32dt + q5][k = f] = w2[f*DH + d]
  f32x16 f2[2];
  #pragma unroll
  for (int dt = 0; dt < 2; ++dt) {
    #pragma unroll
    for (int r = 0; r < 16; ++r) f2[dt][r] = 0.f;
    #pragma unroll
    for (int kk2 = 0; kk2 < 2; ++kk2) {
      bf16x8 aw;
      #pragma unroll
      for (int i = 0; i < 8; ++i)
        aw[i] = (__bf16)w2[(16 * kk2 + 8 * hi + i) * DH + 32 * dt + q5];
      f2[dt] = MFMA32(aw, hb[kk2], f2[dt]);
    }
  }

  // residual2 + LN2 + store
  float v1 = 0.f, v2 = 0.f;
  float val[2][16];
  #pragma unroll
  for (int dt = 0; dt < 2; ++dt)
    #pragma unroll
    for (int r = 0; r < 16; ++r) {
      const float tv = f2[dt][r] + y[dt][r];
      val[dt][r] = tv;
      v1 += tv; v2 += tv * tv;
    }
  v1 += __shfl_xor(v1, 32);
  v2 += __shfl_xor(v2, 32);
  const float mu2   = v1 * (1.f / 64.f);
  const float var2  = v2 * (1.f / 64.f) - mu2 * mu2;
  const float rstd2 = rsqrtf(var2 + 1e-5f);

  float* op = out + ((size_t)(b * NCTX + n)) * DH + 4 * hi;
  #pragma unroll
  for (int dt = 0; dt < 2; ++dt)
    #pragma unroll
    for (int g = 0; g < 4; ++g) {
      f32x4 st;
      #pragma unroll
      for (int j = 0; j < 4; ++j) st[j] = (val[dt][4 * g + j] - mu2) * rstd2;
      *(f32x4*)(op + 32 * dt + 8 * g) = st;
    }
}

// ---------------------------------------------------------------------------
extern "C" void kernel_launch(void* const* d_in, const int* in_sizes, int n_in,
                              void* d_out, int out_size, void* d_ws, size_t ws_size,
                              hipStream_t stream)
{
  const float* x   = (const float*)d_in[0];
  const float* wq  = (const float*)d_in[1];
  const float* wk  = (const float*)d_in[2];
  const float* wv  = (const float*)d_in[3];
  const float* w1  = (const float*)d_in[4];
  const float* w2  = (const float*)d_in[5];
  const float* kpm = (const float*)d_in[6];
  // d_in[7] = causal_mask: handled structurally (triu(k=1) == -1e9 additive)
  float* out = (float*)d_out;

  char* ws = (char*)d_ws;
  const size_t nelem = (size_t)ZB * NCTX * DH;     // 8388608
  __bf16* Qb = (__bf16*)(ws);
  __bf16* Kb = (__bf16*)(ws + nelem * 2);
  __bf16* Vt = (__bf16*)(ws + nelem * 4);          // [Z][D][N]

  const int nblk = ZB * NCTX / 64;                 // 2048
  proj_kernel <<<nblk, 192, 0, stream>>>(x, wq, wk, wv, Qb, Kb, Vt);
  fused_kernel<<<ZB * 32, 128, 0, stream>>>(Qb, Kb, Vt, kpm, x, w1, w2, out);
}

// Round 5
// 203.519 us; speedup vs baseline: 1.3605x; 1.3605x over previous
//
#include <hip/hip_runtime.h>
#include <cstdint>
#include <cstddef>

// Fused transformer block: out = LN(FFN(LN(attn(x)+x)) + LN(attn(x)+x))
// Z=64, N=2048, D=64, DFF=32, causal, single head.
// Kernels: proj (QKV via MFMA -> ws), fused (attn + LN + FFN + LN -> out).
// ws layout: Qb bf16 | Kb bf16 | Vt bf16 [Z][D][N]  (~50 MB)

#define ZB   64
#define NCTX 2048
#define DH   64
#define DFF  32
// base-2 softmax: score*SM_SCALE*log2(e); mask -1e9 pre-scale -> NEGS2 in log2 domain
#define SC2   0.18033688011112042f
#define NEGS2 (-1.8033688e8f)

typedef float f32x4  __attribute__((ext_vector_type(4)));
typedef float f32x16 __attribute__((ext_vector_type(16)));
typedef __bf16 bf16x8 __attribute__((ext_vector_type(8)));
typedef unsigned int u32x4 __attribute__((ext_vector_type(4)));

#define MFMA32(a, b, c) __builtin_amdgcn_mfma_f32_32x32x16_bf16((a), (b), (c), 0, 0, 0)

static __device__ __forceinline__ unsigned cvtpk_bf16(float a, float b) {
  unsigned r;
  asm("v_cvt_pk_bf16_f32 %0, %1, %2" : "=v"(r) : "v"(a), "v"(b));
  return r;
}
static __device__ __forceinline__ void plswap32(unsigned &a, unsigned &b) {
  asm volatile("v_permlane32_swap_b32 %0, %1" : "+v"(a), "+v"(b));
}
static __device__ __forceinline__ float exp2a(float x) {
  float r;
  asm("v_exp_f32 %0, %1" : "=v"(r) : "v"(x));
  return r;
}
// build a bf16x8 frag ordered {own-half, partner-half} by hi from 8 f32 regs
static __device__ __forceinline__ bf16x8 pack_frag(
    float v0, float v1, float v2, float v3,
    float v4, float v5, float v6, float v7) {
  unsigned A0 = cvtpk_bf16(v0, v1), A1 = cvtpk_bf16(v2, v3);
  unsigned B0 = cvtpk_bf16(v4, v5), B1 = cvtpk_bf16(v6, v7);
  plswap32(A0, B0); plswap32(A1, B1);
  u32x4 u = {A0, A1, B0, B1};
  return __builtin_bit_cast(bf16x8, u);
}

// ---------------------------------------------------------------------------
// Kernel 1: QKV projection via MFMA. grid = 1024 x 256 (4 waves), wave = one
// 32-token tile. C[e][n] = sum_d w[d][e] x[n][d]: A-frag = weight cols
// (8 scalar loads, L1-hot), B-frag = x row chunk (2 x f32x4 -> cvt_pk).
// Q/K stored row-major bf16 via cvt_pk+permlane32_swap pack (lane covers
// e in [32hi, 32hi+32) of its token); V stored transposed [b][d][n] via
// scalar 2B stores (lanes of equal (hi,reg) -> 64B-contiguous lines).
// ---------------------------------------------------------------------------
__global__ __launch_bounds__(256) void proj_kernel(
    const float* __restrict__ x, const float* __restrict__ wq,
    const float* __restrict__ wk, const float* __restrict__ wv,
    __bf16* __restrict__ Qb, __bf16* __restrict__ Kb, __bf16* __restrict__ Vt)
{
  const int wid = threadIdx.x >> 6;
  const int l   = threadIdx.x & 63;
  const int q5  = l & 31, hi = l >> 5;
  const int tile = blockIdx.x * 4 + wid;        // 4096 tiles of 32 tokens
  const int b   = tile >> 6;                    // 64 tiles per batch
  const int n0  = (tile & 63) << 5;
  const int n   = n0 + q5;                      // this lane's token

  // x B-frags: element i of frag kk = x[n][16kk + 8hi + i]
  const float* xr = x + ((size_t)(b * NCTX + n)) * DH + 8 * hi;
  bf16x8 xb[4];
  #pragma unroll
  for (int kk = 0; kk < 4; ++kk) {
    const f32x4 a = *(const f32x4*)(xr + 16 * kk);
    const f32x4 c = *(const f32x4*)(xr + 16 * kk + 4);
    u32x4 u = {cvtpk_bf16(a[0], a[1]), cvtpk_bf16(a[2], a[3]),
               cvtpk_bf16(c[0], c[1]), cvtpk_bf16(c[2], c[3])};
    xb[kk] = __builtin_bit_cast(bf16x8, u);
  }

  const size_t rowb = ((size_t)(b * NCTX + n)) * DH;

  #pragma unroll
  for (int m = 0; m < 3; ++m) {
    const float* w = (m == 0) ? wq : (m == 1) ? wk : wv;

    f32x16 c0, c1;
    #pragma unroll
    for (int r = 0; r < 16; ++r) { c0[r] = 0.f; c1[r] = 0.f; }

    #pragma unroll
    for (int kk = 0; kk < 4; ++kk) {
      // A-frag (et): element i = w[(16kk + 8hi + i)*64 + 32et + q5]
      const float* wp = w + (size_t)(16 * kk + 8 * hi) * DH + q5;
      float f0[8], f1[8];
      #pragma unroll
      for (int i = 0; i < 8; ++i) { f0[i] = wp[i * DH]; f1[i] = wp[i * DH + 32]; }
      u32x4 ua = {cvtpk_bf16(f0[0], f0[1]), cvtpk_bf16(f0[2], f0[3]),
                  cvtpk_bf16(f0[4], f0[5]), cvtpk_bf16(f0[6], f0[7])};
      u32x4 ub = {cvtpk_bf16(f1[0], f1[1]), cvtpk_bf16(f1[2], f1[3]),
                  cvtpk_bf16(f1[4], f1[5]), cvtpk_bf16(f1[6], f1[7])};
      c0 = MFMA32(__builtin_bit_cast(bf16x8, ua), xb[kk], c0);
      c1 = MFMA32(__builtin_bit_cast(bf16x8, ub), xb[kk], c1);
    }

    if (m < 2) {
      // row-major store: lane covers e in [32hi, 32hi+32) of token n
      __bf16* dst = ((m == 0) ? Qb : Kb) + rowb + 32 * hi;
      #pragma unroll
      for (int g = 0; g < 4; ++g) {
        unsigned A0 = cvtpk_bf16(c0[4 * g],     c0[4 * g + 1]);
        unsigned A1 = cvtpk_bf16(c0[4 * g + 2], c0[4 * g + 3]);
        unsigned B0 = cvtpk_bf16(c1[4 * g],     c1[4 * g + 1]);
        unsigned B1 = cvtpk_bf16(c1[4 * g + 2], c1[4 * g + 3]);
        plswap32(A0, B0); plswap32(A1, B1);
        u32x4 u = {A0, A1, B0, B1};
        *(u32x4*)(dst + 8 * g) = u;
      }
    } else {
      // V^T store: Vt[b][d][n], d = 32et + (r&3) + 8(r>>2) + 4hi
      __bf16* vb = Vt + (size_t)b * DH * NCTX + n;
      #pragma unroll
      for (int r = 0; r < 16; ++r) {
        const int d = (r & 3) + 8 * (r >> 2) + 4 * hi;
        vb[(size_t)d * NCTX]        = (__bf16)c0[r];
        vb[(size_t)(d + 32) * NCTX] = (__bf16)c1[r];
      }
    }
  }
}

// ---------------------------------------------------------------------------
// Kernel 2: fused causal flash attention + LN + FFN + LN.
// grid = Z*32 blocks x 128 threads (2 waves). Wave 0 -> q-tile tp, wave 1 ->
// q-tile 63-tp (balanced: every block = 65 kv-tile iterations). No LDS.
// Attn: S^T = mfma32(K,Q), in-register base-2 online softmax (lane owns q-row
// l&31, partner l^32 holds other half), O^T = mfma32(V^T, P^T), defer-max.
// K-tile fragments double-buffered: next tile's loads issue right after the
// current QK MFMAs, hiding L2 latency under softmax+PV (the round-4 critical
// path). V loads stay early-issue within the iteration.
// Epilogue (per wave, in-register): y = LN(O+x); h^T = relu(mfma32(w1^T, y));
// ff^T = mfma32(w2^T, h^T); out = LN(ff + y). Zero LDS, no intermediate HBM.
// ---------------------------------------------------------------------------
__global__ __launch_bounds__(128) void fused_kernel(
    const __bf16* __restrict__ Qb, const __bf16* __restrict__ Kb,
    const __bf16* __restrict__ Vt, const float* __restrict__ kpm,
    const float* __restrict__ x,  const float* __restrict__ w1,
    const float* __restrict__ w2, float* __restrict__ out)
{
  const int bid = (blockIdx.x & 7) * 256 + (blockIdx.x >> 3);  // XCD chunking
  const int b   = bid >> 5;
  const int tp  = bid & 31;
  const int wv  = threadIdx.x >> 6;
  const int l   = threadIdx.x & 63;
  const int q5  = l & 31;
  const int hi  = l >> 5;
  const int t   = wv ? (63 - tp) : tp;
  const int qw  = t << 5;
  const int n   = qw + q5;                  // this lane's q row

  // Q fragments: lane supplies Q[n][16c + 8hi + i]  (B-operand, col = q)
  const __bf16* qp = Qb + ((size_t)(b * NCTX + n)) * DH + hi * 8;
  bf16x8 qf[4];
  #pragma unroll
  for (int c = 0; c < 4; ++c) qf[c] = *(const bf16x8*)(qp + 16 * c);

  f32x16 acc[2];
  #pragma unroll
  for (int r = 0; r < 16; ++r) { acc[0][r] = 0.f; acc[1][r] = 0.f; }
  float m_run = -1e30f, ls = 0.f;

  const float*  kpb   = kpm + b * NCTX;
  const __bf16* kbase = Kb + ((size_t)b * NCTX + q5) * DH + hi * 8;
  const __bf16* vbase = Vt + ((size_t)(b * DH + q5)) * NCTX + hi * 8;

  // prime K double-buffer with tile kv0 = 0
  bf16x8 kc[4];
  #pragma unroll
  for (int c = 0; c < 4; ++c) kc[c] = *(const bf16x8*)(kbase + 16 * c);

  for (int kv0 = 0; kv0 <= qw; kv0 += 32) {
    const bool diag = (kv0 == qw);          // wave-uniform

    // V B-frags issued EARLY (independent addresses) to hide latency
    const __bf16* vp = vbase + kv0;
    const bf16x8 vf0 = *(const bf16x8*)(vp);
    const bf16x8 vf1 = *(const bf16x8*)(vp + 16);
    const bf16x8 vf2 = *(const bf16x8*)(vp + (size_t)32 * NCTX);
    const bf16x8 vf3 = *(const bf16x8*)(vp + (size_t)32 * NCTX + 16);

    // S^T = K_tile . Q^T : 4 MFMAs over D=64 (uses pre-loaded kc)
    f32x16 s;
    #pragma unroll
    for (int r = 0; r < 16; ++r) s[r] = 0.f;
    #pragma unroll
    for (int c = 0; c < 4; ++c) s = MFMA32(kc[c], qf[c], s);

    // prefetch NEXT K tile while softmax+PV run (round-4 critical path fix)
    const bool hasnext = (kv0 + 32 <= qw);
    bf16x8 kn[4];
    if (hasnext) {
      const __bf16* kp = kbase + (size_t)(kv0 + 32) * DH;
      #pragma unroll
      for (int c = 0; c < 4; ++c) kn[c] = *(const bf16x8*)(kp + 16 * c);
    }

    // key-padding-mask values for this lane's 16 kv slots (reg r -> kv rm(r))
    f32x4 kb[4];
    #pragma unroll
    for (int g = 0; g < 4; ++g)
      kb[g] = *(const f32x4*)(kpb + kv0 + 4 * hi + 8 * g);

    float p[16];
    #pragma unroll
    for (int r = 0; r < 16; ++r) {
      float tv = (s[r] + kb[r >> 2][r & 3]) * SC2;
      if (diag) {
        const int rm = (r & 3) + 8 * (r >> 2) + 4 * hi;   // kv offset in tile
        tv = (rm > q5) ? tv + NEGS2 : tv;                 // causal: j > i
      }
      p[r] = tv;
    }

    // row max: in-lane tree + partner exchange
    float m0 = fmaxf(fmaxf(p[0], p[1]),  fmaxf(p[2], p[3]));
    float m1 = fmaxf(fmaxf(p[4], p[5]),  fmaxf(p[6], p[7]));
    float m2 = fmaxf(fmaxf(p[8], p[9]),  fmaxf(p[10], p[11]));
    float m3 = fmaxf(fmaxf(p[12], p[13]), fmaxf(p[14], p[15]));
    float mx = fmaxf(fmaxf(m0, m1), fmaxf(m2, m3));
    mx = fmaxf(mx, __shfl_xor(mx, 32));

    if (!__all(mx <= m_run + 11.0f)) {      // defer-max (T13)
      const float mn = fmaxf(m_run, mx);
      const float sc = exp2a(m_run - mn);   // first iter: exp2(-1e30)=0
      m_run = mn;
      ls *= sc;
      #pragma unroll
      for (int r = 0; r < 16; ++r) { acc[0][r] *= sc; acc[1][r] *= sc; }
    }

    #pragma unroll
    for (int r = 0; r < 16; ++r) p[r] = exp2a(p[r] - m_run);
    float t0 = (p[0] + p[1])  + (p[2] + p[3]);
    float t1 = (p[4] + p[5])  + (p[6] + p[7]);
    float t2 = (p[8] + p[9])  + (p[10] + p[11]);
    float t3 = (p[12] + p[13]) + (p[14] + p[15]);
    float rs = (t0 + t1) + (t2 + t3);
    rs += __shfl_xor(rs, 32);
    ls += rs;

    // P^T -> bf16 B-frags (kv 0..15 and 16..31) via cvt_pk + permlane32_swap
    const bf16x8 pf0 = pack_frag(p[0], p[1], p[2],  p[3],  p[4],  p[5],  p[6],  p[7]);
    const bf16x8 pf1 = pack_frag(p[8], p[9], p[10], p[11], p[12], p[13], p[14], p[15]);

    // O^T += V^T . P^T : A-frag = Vt rows (d), 2 d-blocks x 2 kv-halves
    acc[0] = MFMA32(vf0, pf0, acc[0]);
    acc[0] = MFMA32(vf1, pf1, acc[0]);
    acc[1] = MFMA32(vf2, pf0, acc[1]);
    acc[1] = MFMA32(vf3, pf1, acc[1]);

    if (hasnext) {
      #pragma unroll
      for (int c = 0; c < 4; ++c) kc[c] = kn[c];
    }
  }

  // ------------------ fused epilogue: LN1 + FFN + LN2 ------------------
  // lane layout: value (db, r) lives at d = 32db + 8(r>>2) + 4hi + (r&3);
  // partner lane (l^32) holds the other 4-offsets -> row ops = in-lane + shfl(32).
  const float invl = 1.f / ls;
  const float* xrow = x + ((size_t)(b * NCTX + n)) * DH;

  // residual1: t = O + x ; LN over d=64
  float y[2][16];
  float s1 = 0.f, s2 = 0.f;
  #pragma unroll
  for (int db = 0; db < 2; ++db)
    #pragma unroll
    for (int g = 0; g < 4; ++g) {
      const f32x4 xv = *(const f32x4*)(xrow + 32 * db + 8 * g + 4 * hi);
      #pragma unroll
      for (int j = 0; j < 4; ++j) {
        const float tv = acc[db][4 * g + j] * invl + xv[j];
        y[db][4 * g + j] = tv;
        s1 += tv; s2 += tv * tv;
      }
    }
  s1 += __shfl_xor(s1, 32);
  s2 += __shfl_xor(s2, 32);
  {
    const float mu   = s1 * (1.f / 64.f);
    const float var  = s2 * (1.f / 64.f) - mu * mu;
    const float rstd = rsqrtf(var + 1e-5f);
    #pragma unroll
    for (int db = 0; db < 2; ++db)
      #pragma unroll
      for (int r = 0; r < 16; ++r) y[db][r] = (y[db][r] - mu) * rstd;
  }

  // y -> bf16 frags: yb[kk] supplies [row n][k = 16kk + 8hi + i]
  bf16x8 yb[4];
  #pragma unroll
  for (int kk = 0; kk < 4; ++kk) {
    const int db = kk >> 1, rb = 8 * (kk & 1);
    yb[kk] = pack_frag(y[db][rb + 0], y[db][rb + 1], y[db][rb + 2], y[db][rb + 3],
                       y[db][rb + 4], y[db][rb + 5], y[db][rb + 6], y[db][rb + 7]);
  }

  // w1^T A-frags: A[f = q5][k = d] = w1[d*DFF + f]
  f32x16 hc;
  #pragma unroll
  for (int r = 0; r < 16; ++r) hc[r] = 0.f;
  #pragma unroll
  for (int kk = 0; kk < 4; ++kk) {
    bf16x8 aw;
    #pragma unroll
    for (int i = 0; i < 8; ++i)
      aw[i] = (__bf16)w1[(16 * kk + 8 * hi + i) * DFF + q5];
    hc = MFMA32(aw, yb[kk], hc);
  }
  // h^T: lane owns col q (= n), rows f = 8(r>>2)+4hi+(r&3); relu
  float hv[16];
  #pragma unroll
  for (int r = 0; r < 16; ++r) hv[r] = fmaxf(hc[r], 0.f);

  // h -> bf16 frags (k = f): hb[kk2] supplies [col n][k = 16kk2 + 8hi + i]
  bf16x8 hb[2];
  #pragma unroll
  for (int kk2 = 0; kk2 < 2; ++kk2) {
    const int rb = 8 * kk2;
    hb[kk2] = pack_frag(hv[rb + 0], hv[rb + 1], hv[rb + 2], hv[rb + 3],
                        hv[rb + 4], hv[rb + 5], hv[rb + 6], hv[rb + 7]);
  }

  // ff^T = w2^T . h^T : A[d = 32dt + q5][k = f] = w2[f*DH + d]
  f32x16 f2[2];
  #pragma unroll
  for (int dt = 0; dt < 2; ++dt) {
    #pragma unroll
    for (int r = 0; r < 16; ++r) f2[dt][r] = 0.f;
    #pragma unroll
    for (int kk2 = 0; kk2 < 2; ++kk2) {
      bf16x8 aw;
      #pragma unroll
      for (int i = 0; i < 8; ++i)
        aw[i] = (__bf16)w2[(16 * kk2 + 8 * hi + i) * DH + 32 * dt + q5];
      f2[dt] = MFMA32(aw, hb[kk2], f2[dt]);
    }
  }

  // residual2 + LN2 + store
  float v1 = 0.f, v2 = 0.f;
  float val[2][16];
  #pragma unroll
  for (int dt = 0; dt < 2; ++dt)
    #pragma unroll
    for (int r = 0; r < 16; ++r) {
      const float tv = f2[dt][r] + y[dt][r];
      val[dt][r] = tv;
      v1 += tv; v2 += tv * tv;
    }
  v1 += __shfl_xor(v1, 32);
  v2 += __shfl_xor(v2, 32);
  const float mu2   = v1 * (1.f / 64.f);
  const float var2  = v2 * (1.f / 64.f) - mu2 * mu2;
  const float rstd2 = rsqrtf(var2 + 1e-5f);

  float* op = out + ((size_t)(b * NCTX + n)) * DH + 4 * hi;
  #pragma unroll
  for (int dt = 0; dt < 2; ++dt)
    #pragma unroll
    for (int g = 0; g < 4; ++g) {
      f32x4 st;
      #pragma unroll
      for (int j = 0; j < 4; ++j) st[j] = (val[dt][4 * g + j] - mu2) * rstd2;
      *(f32x4*)(op + 32 * dt + 8 * g) = st;
    }
}

// ---------------------------------------------------------------------------
extern "C" void kernel_launch(void* const* d_in, const int* in_sizes, int n_in,
                              void* d_out, int out_size, void* d_ws, size_t ws_size,
                              hipStream_t stream)
{
  const float* x   = (const float*)d_in[0];
  const float* wq  = (const float*)d_in[1];
  const float* wk  = (const float*)d_in[2];
  const float* wv  = (const float*)d_in[3];
  const float* w1  = (const float*)d_in[4];
  const float* w2  = (const float*)d_in[5];
  const float* kpm = (const float*)d_in[6];
  // d_in[7] = causal_mask: handled structurally (triu(k=1) == -1e9 additive)
  float* out = (float*)d_out;

  char* ws = (char*)d_ws;
  const size_t nelem = (size_t)ZB * NCTX * DH;     // 8388608
  __bf16* Qb = (__bf16*)(ws);
  __bf16* Kb = (__bf16*)(ws + nelem * 2);
  __bf16* Vt = (__bf16*)(ws + nelem * 4);          // [Z][D][N]

  proj_kernel <<<1024, 256, 0, stream>>>(x, wq, wk, wv, Qb, Kb, Vt);
  fused_kernel<<<ZB * 32, 128, 0, stream>>>(Qb, Kb, Vt, kpm, x, w1, w2, out);
}

// Round 7
// 202.800 us; speedup vs baseline: 1.3653x; 1.0035x over previous
//
#include <hip/hip_runtime.h>
#include <cstdint>
#include <cstddef>

// Fused transformer block: out = LN(FFN(LN(attn(x)+x)) + LN(attn(x)+x))
// Z=64, N=2048, D=64, DFF=32, causal, single head.
// Kernels: proj (QKV via MFMA + weight/kpm prep), fused (attn+LN+FFN+LN).
// ws: Qb bf16 (Q pre-scaled by SC2) | Kb | Vt [Z][D][N] | kpmS f32 | w1p | w2p

#define ZB   64
#define NCTX 2048
#define DH   64
#define DFF  32
// base-2 softmax: score*SM_SCALE*log2(e); mask -1e9 pre-scale -> NEGS2 in log2 domain
#define SC2   0.18033688011112042f
#define NEGS2 (-1.8033688e8f)

typedef float f32x4  __attribute__((ext_vector_type(4)));
typedef float f32x16 __attribute__((ext_vector_type(16)));
typedef __bf16 bf16x8 __attribute__((ext_vector_type(8)));
typedef unsigned int u32x4 __attribute__((ext_vector_type(4)));

#define MFMA32(a, b, c) __builtin_amdgcn_mfma_f32_32x32x16_bf16((a), (b), (c), 0, 0, 0)

static __device__ __forceinline__ unsigned cvtpk_bf16(float a, float b) {
  unsigned r;
  asm("v_cvt_pk_bf16_f32 %0, %1, %2" : "=v"(r) : "v"(a), "v"(b));
  return r;
}
static __device__ __forceinline__ void plswap32(unsigned &a, unsigned &b) {
  asm volatile("v_permlane32_swap_b32 %0, %1" : "+v"(a), "+v"(b));
}
static __device__ __forceinline__ float exp2a(float x) {
  float r;
  asm("v_exp_f32 %0, %1" : "=v"(r) : "v"(x));
  return r;
}
// lane^32 reductions via ds_bpermute shuffle (round-3..5-proven correct)
static __device__ __forceinline__ float redmax32(float v) {
  return fmaxf(v, __shfl_xor(v, 32));
}
static __device__ __forceinline__ float redsum32(float v) {
  return v + __shfl_xor(v, 32);
}
// build a bf16x8 frag ordered {own-half, partner-half} from 8 f32 regs whose
// local row is rm = (r&3) + 8*(r>>2) + 4*hi (the 32x32 C-layout pattern)
static __device__ __forceinline__ bf16x8 pack_frag(
    float v0, float v1, float v2, float v3,
    float v4, float v5, float v6, float v7) {
  unsigned A0 = cvtpk_bf16(v0, v1), A1 = cvtpk_bf16(v2, v3);
  unsigned B0 = cvtpk_bf16(v4, v5), B1 = cvtpk_bf16(v6, v7);
  plswap32(A0, B0); plswap32(A1, B1);
  u32x4 u = {A0, A1, B0, B1};
  return __builtin_bit_cast(bf16x8, u);
}

// ---------------------------------------------------------------------------
// Kernel 1: QKV projection via MFMA (grid 1024 x 256, wave = 32-token tile).
// Also: Q pre-scaled by SC2; kpmS = kpm*SC2; block 0 wave 0 packs w1/w2 into
// MFMA-frag layout (w1p[kk][lane][8], w2p[dt*2+kk2][lane][8]) for the fused
// epilogue's coalesced 16B frag loads.
// ---------------------------------------------------------------------------
__global__ __launch_bounds__(256) void proj_kernel(
    const float* __restrict__ x, const float* __restrict__ wq,
    const float* __restrict__ wk, const float* __restrict__ wv,
    const float* __restrict__ w1, const float* __restrict__ w2,
    const float* __restrict__ kpm,
    __bf16* __restrict__ Qb, __bf16* __restrict__ Kb, __bf16* __restrict__ Vt,
    float* __restrict__ kpmS, __bf16* __restrict__ w1p, __bf16* __restrict__ w2p)
{
  const int wid = threadIdx.x >> 6;
  const int l   = threadIdx.x & 63;
  const int q5  = l & 31, hi = l >> 5;
  const int tile = blockIdx.x * 4 + wid;        // 4096 tiles of 32 tokens
  const int b   = tile >> 6;                    // 64 tiles per batch
  const int n0  = (tile & 63) << 5;
  const int n   = n0 + q5;                      // this lane's token

  // weight frag prep (one wave, once)
  if (blockIdx.x == 0 && wid == 0) {
    #pragma unroll
    for (int kk = 0; kk < 4; ++kk)
      #pragma unroll
      for (int i = 0; i < 8; ++i)
        w1p[(kk * 64 + l) * 8 + i] = (__bf16)w1[(16 * kk + 8 * hi + i) * DFF + q5];
    #pragma unroll
    for (int dt = 0; dt < 2; ++dt)
      #pragma unroll
      for (int kk2 = 0; kk2 < 2; ++kk2)
        #pragma unroll
        for (int i = 0; i < 8; ++i)
          w2p[((dt * 2 + kk2) * 64 + l) * 8 + i] =
              (__bf16)w2[(16 * kk2 + 8 * hi + i) * DH + 32 * dt + q5];
  }
  // kpmS: each token written once (lanes hi==0 of its tile's wave)
  if (hi == 0) kpmS[b * NCTX + n] = kpm[b * NCTX + n] * SC2;

  // x B-frags: element i of frag kk = x[n][16kk + 8hi + i]
  const float* xr = x + ((size_t)(b * NCTX + n)) * DH + 8 * hi;
  bf16x8 xb[4];
  #pragma unroll
  for (int kk = 0; kk < 4; ++kk) {
    const f32x4 a = *(const f32x4*)(xr + 16 * kk);
    const f32x4 c = *(const f32x4*)(xr + 16 * kk + 4);
    u32x4 u = {cvtpk_bf16(a[0], a[1]), cvtpk_bf16(a[2], a[3]),
               cvtpk_bf16(c[0], c[1]), cvtpk_bf16(c[2], c[3])};
    xb[kk] = __builtin_bit_cast(bf16x8, u);
  }

  const size_t rowb = ((size_t)(b * NCTX + n)) * DH;

  #pragma unroll
  for (int m = 0; m < 3; ++m) {
    const float* w = (m == 0) ? wq : (m == 1) ? wk : wv;

    f32x16 c0, c1;
    #pragma unroll
    for (int r = 0; r < 16; ++r) { c0[r] = 0.f; c1[r] = 0.f; }

    #pragma unroll
    for (int kk = 0; kk < 4; ++kk) {
      const float* wp = w + (size_t)(16 * kk + 8 * hi) * DH + q5;
      float f0[8], f1[8];
      #pragma unroll
      for (int i = 0; i < 8; ++i) { f0[i] = wp[i * DH]; f1[i] = wp[i * DH + 32]; }
      u32x4 ua = {cvtpk_bf16(f0[0], f0[1]), cvtpk_bf16(f0[2], f0[3]),
                  cvtpk_bf16(f0[4], f0[5]), cvtpk_bf16(f0[6], f0[7])};
      u32x4 ub = {cvtpk_bf16(f1[0], f1[1]), cvtpk_bf16(f1[2], f1[3]),
                  cvtpk_bf16(f1[4], f1[5]), cvtpk_bf16(f1[6], f1[7])};
      c0 = MFMA32(__builtin_bit_cast(bf16x8, ua), xb[kk], c0);
      c1 = MFMA32(__builtin_bit_cast(bf16x8, ub), xb[kk], c1);
    }

    if (m == 0) {  // fold softmax scale into Q
      #pragma unroll
      for (int r = 0; r < 16; ++r) { c0[r] *= SC2; c1[r] *= SC2; }
    }

    if (m < 2) {
      __bf16* dst = ((m == 0) ? Qb : Kb) + rowb + 32 * hi;
      #pragma unroll
      for (int g = 0; g < 4; ++g) {
        unsigned A0 = cvtpk_bf16(c0[4 * g],     c0[4 * g + 1]);
        unsigned A1 = cvtpk_bf16(c0[4 * g + 2], c0[4 * g + 3]);
        unsigned B0 = cvtpk_bf16(c1[4 * g],     c1[4 * g + 1]);
        unsigned B1 = cvtpk_bf16(c1[4 * g + 2], c1[4 * g + 3]);
        plswap32(A0, B0); plswap32(A1, B1);
        u32x4 u = {A0, A1, B0, B1};
        *(u32x4*)(dst + 8 * g) = u;
      }
    } else {
      __bf16* vb = Vt + (size_t)b * DH * NCTX + n;
      #pragma unroll
      for (int r = 0; r < 16; ++r) {
        const int d = (r & 3) + 8 * (r >> 2) + 4 * hi;
        vb[(size_t)d * NCTX]        = (__bf16)c0[r];
        vb[(size_t)(d + 32) * NCTX] = (__bf16)c1[r];
      }
    }
  }
}

// ---------------------------------------------------------------------------
// Kernel 2: fused causal flash attention + LN + FFN + LN.
// grid = Z*32 x 128 (2 waves; wave 0 -> tile tp, wave 1 -> tile 63-tp). No LDS.
// 2-stage pipeline: QK MFMAs for tile j+1 issue BEFORE the softmax VALU of
// tile j (MFMA pipe overlaps VALU chain); K frags ping-pong via 2x-unrolled
// loop (no copies). Softmax in-register, base-2, defer-max; lane^32
// reductions via shfl_xor (proven); P/y/h repacks via cvt_pk+permlane32_swap
// (distinct-operand form, proven). Epilogue FFN uses pre-packed weight frags.
// ---------------------------------------------------------------------------
__global__ __launch_bounds__(128) void fused_kernel(
    const __bf16* __restrict__ Qb, const __bf16* __restrict__ Kb,
    const __bf16* __restrict__ Vt, const float* __restrict__ kpmS,
    const float* __restrict__ x,
    const __bf16* __restrict__ w1p, const __bf16* __restrict__ w2p,
    float* __restrict__ out)
{
  const int bid = (blockIdx.x & 7) * 256 + (blockIdx.x >> 3);  // XCD chunking
  const int b   = bid >> 5;
  const int tp  = bid & 31;
  const int wv  = threadIdx.x >> 6;
  const int l   = threadIdx.x & 63;
  const int q5  = l & 31;
  const int hi  = l >> 5;
  const int t   = wv ? (63 - tp) : tp;
  const int qw  = t << 5;
  const int n   = qw + q5;                  // this lane's q row

  // Q fragments (pre-scaled by SC2 in proj): Q[n][16c + 8hi + i]
  const __bf16* qp = Qb + ((size_t)(b * NCTX + n)) * DH + hi * 8;
  const bf16x8 qf0 = *(const bf16x8*)(qp);
  const bf16x8 qf1 = *(const bf16x8*)(qp + 16);
  const bf16x8 qf2 = *(const bf16x8*)(qp + 32);
  const bf16x8 qf3 = *(const bf16x8*)(qp + 48);

  f32x16 acc0, acc1, z16;
  #pragma unroll
  for (int r = 0; r < 16; ++r) { acc0[r] = 0.f; acc1[r] = 0.f; z16[r] = 0.f; }
  float m_run = -1e30f, ls = 0.f;

  const float*  kpb   = kpmS + b * NCTX;
  const __bf16* kbase = Kb + ((size_t)b * NCTX + q5) * DH + hi * 8;
  const __bf16* vbase = Vt + ((size_t)(b * DH + q5)) * NCTX + hi * 8;

  bf16x8 kA0, kA1, kA2, kA3, kB0, kB1, kB2, kB3;

#define LOADK(f0, f1, f2, f3, KV) do {                                  \
    const __bf16* _kp = kbase + (size_t)(KV) * DH;                      \
    f0 = *(const bf16x8*)(_kp);      f1 = *(const bf16x8*)(_kp + 16);   \
    f2 = *(const bf16x8*)(_kp + 32); f3 = *(const bf16x8*)(_kp + 48);   \
  } while (0)

#define QK(S, f0, f1, f2, f3) do {  \
    S = MFMA32(f0, qf0, z16);       \
    S = MFMA32(f1, qf1, S);         \
    S = MFMA32(f2, qf2, S);         \
    S = MFMA32(f3, qf3, S);         \
  } while (0)

  // causal mask for the diagonal tile (additive pre-scale -1e9 -> NEGS2)
  auto diagmask = [&](f32x16& s) {
    #pragma unroll
    for (int r = 0; r < 16; ++r) {
      const int rm = (r & 3) + 8 * (r >> 2) + 4 * hi;
      s[r] = (rm > q5) ? s[r] + NEGS2 : s[r];
    }
  };

  // softmax + PV for one scored tile
  auto consume = [&](const f32x16& s, int kv0) {
    const __bf16* vp = vbase + kv0;
    const bf16x8 vf0 = *(const bf16x8*)(vp);
    const bf16x8 vf1 = *(const bf16x8*)(vp + 16);
    const bf16x8 vf2 = *(const bf16x8*)(vp + (size_t)32 * NCTX);
    const bf16x8 vf3 = *(const bf16x8*)(vp + (size_t)32 * NCTX + 16);
    const float* kp2 = kpb + kv0 + 4 * hi;
    const f32x4 kb0 = *(const f32x4*)(kp2);
    const f32x4 kb1 = *(const f32x4*)(kp2 + 8);
    const f32x4 kb2 = *(const f32x4*)(kp2 + 16);
    const f32x4 kb3 = *(const f32x4*)(kp2 + 24);

    float p[16];
    #pragma unroll
    for (int j = 0; j < 4; ++j) {
      p[j]      = s[j]      + kb0[j];
      p[4 + j]  = s[4 + j]  + kb1[j];
      p[8 + j]  = s[8 + j]  + kb2[j];
      p[12 + j] = s[12 + j] + kb3[j];
    }

    // row max: nested fmaxf (v_max3-fusable) + partner half via shfl
    float ma = fmaxf(fmaxf(p[0],  p[1]),  p[2]);
    float mb = fmaxf(fmaxf(p[3],  p[4]),  p[5]);
    float mc = fmaxf(fmaxf(p[6],  p[7]),  p[8]);
    float md = fmaxf(fmaxf(p[9],  p[10]), p[11]);
    float me = fmaxf(fmaxf(p[12], p[13]), p[14]);
    float mx = fmaxf(fmaxf(ma, mb), mc);
    mx = fmaxf(fmaxf(mx, md), me);
    mx = fmaxf(mx, p[15]);
    mx = redmax32(mx);

    if (!__all(mx <= m_run + 11.0f)) {      // defer-max (T13)
      const float mn = fmaxf(m_run, mx);
      const float sc = exp2a(m_run - mn);   // first tile: exp2(-1e30)=0
      m_run = mn;
      ls *= sc;
      #pragma unroll
      for (int r = 0; r < 16; ++r) { acc0[r] *= sc; acc1[r] *= sc; }
    }

    #pragma unroll
    for (int r = 0; r < 16; ++r) p[r] = exp2a(p[r] - m_run);
    float rs = ((p[0] + p[1]) + (p[2] + p[3])) + ((p[4] + p[5]) + (p[6] + p[7]))
             + ((p[8] + p[9]) + (p[10] + p[11])) + ((p[12] + p[13]) + (p[14] + p[15]));
    ls += redsum32(rs);

    const bf16x8 pf0 = pack_frag(p[0], p[1], p[2],  p[3],  p[4],  p[5],  p[6],  p[7]);
    const bf16x8 pf1 = pack_frag(p[8], p[9], p[10], p[11], p[12], p[13], p[14], p[15]);

    acc0 = MFMA32(vf0, pf0, acc0);
    acc0 = MFMA32(vf1, pf1, acc0);
    acc1 = MFMA32(vf2, pf0, acc1);
    acc1 = MFMA32(vf3, pf1, acc1);
  };

  // ---- pipelined kv loop: tiles 0..T-1, T = t+1 ----
  const int T = t + 1;
  f32x16 sA, sB;
  LOADK(kA0, kA1, kA2, kA3, 0);
  QK(sA, kA0, kA1, kA2, kA3);
  if (T == 1) {
    diagmask(sA);
    consume(sA, 0);
  } else {
    LOADK(kB0, kB1, kB2, kB3, 32);
    int j = 0;
    for (;;) {
      if (j + 2 < T) LOADK(kA0, kA1, kA2, kA3, 32 * (j + 2));
      QK(sB, kB0, kB1, kB2, kB3);        // MFMA pipe: overlaps consume's VALU
      consume(sA, 32 * j);
      ++j;
      if (j + 1 == T) { diagmask(sB); consume(sB, 32 * j); break; }
      if (j + 2 < T) LOADK(kB0, kB1, kB2, kB3, 32 * (j + 2));
      QK(sA, kA0, kA1, kA2, kA3);
      consume(sB, 32 * j);
      ++j;
      if (j + 1 == T) { diagmask(sA); consume(sA, 32 * j); break; }
    }
  }

  // ------------------ fused epilogue: LN1 + FFN + LN2 ------------------
  // value (db, r) lives at d = 32db + 8(r>>2) + 4hi + (r&3); partner lane
  // (l^32) holds the other half -> row reductions via shfl_xor(32).
  const float invl = 1.f / ls;
  const float* xrow = x + ((size_t)(b * NCTX + n)) * DH;

  float y0[16], y1[16];
  float s1 = 0.f, s2 = 0.f;
  #pragma unroll
  for (int g = 0; g < 4; ++g) {
    const f32x4 xv0 = *(const f32x4*)(xrow + 8 * g + 4 * hi);
    const f32x4 xv1 = *(const f32x4*)(xrow + 32 + 8 * g + 4 * hi);
    #pragma unroll
    for (int j = 0; j < 4; ++j) {
      const float a0 = acc0[4 * g + j] * invl + xv0[j];
      const float a1 = acc1[4 * g + j] * invl + xv1[j];
      y0[4 * g + j] = a0; y1[4 * g + j] = a1;
      s1 += a0 + a1; s2 += a0 * a0 + a1 * a1;
    }
  }
  s1 = redsum32(s1);
  s2 = redsum32(s2);
  {
    const float mu   = s1 * (1.f / 64.f);
    const float var  = s2 * (1.f / 64.f) - mu * mu;
    const float rstd = rsqrtf(var + 1e-5f);
    #pragma unroll
    for (int r = 0; r < 16; ++r) {
      y0[r] = (y0[r] - mu) * rstd;
      y1[r] = (y1[r] - mu) * rstd;
    }
  }

  const bf16x8 yb0 = pack_frag(y0[0], y0[1], y0[2],  y0[3],  y0[4],  y0[5],  y0[6],  y0[7]);
  const bf16x8 yb1 = pack_frag(y0[8], y0[9], y0[10], y0[11], y0[12], y0[13], y0[14], y0[15]);
  const bf16x8 yb2 = pack_frag(y1[0], y1[1], y1[2],  y1[3],  y1[4],  y1[5],  y1[6],  y1[7]);
  const bf16x8 yb3 = pack_frag(y1[8], y1[9], y1[10], y1[11], y1[12], y1[13], y1[14], y1[15]);

  // h^T = relu(w1^T . y^T): coalesced pre-packed frags
  const __bf16* wp1 = w1p + (size_t)l * 8;
  f32x16 hc;
  hc = MFMA32(*(const bf16x8*)(wp1),               yb0, z16);
  hc = MFMA32(*(const bf16x8*)(wp1 + 64 * 8),      yb1, hc);
  hc = MFMA32(*(const bf16x8*)(wp1 + 2 * 64 * 8),  yb2, hc);
  hc = MFMA32(*(const bf16x8*)(wp1 + 3 * 64 * 8),  yb3, hc);
  float hv[16];
  #pragma unroll
  for (int r = 0; r < 16; ++r) hv[r] = fmaxf(hc[r], 0.f);

  const bf16x8 hb0 = pack_frag(hv[0], hv[1], hv[2],  hv[3],  hv[4],  hv[5],  hv[6],  hv[7]);
  const bf16x8 hb1 = pack_frag(hv[8], hv[9], hv[10], hv[11], hv[12], hv[13], hv[14], hv[15]);

  // ff^T = w2^T . h^T
  const __bf16* wp2 = w2p + (size_t)l * 8;
  f32x16 f20, f21;
  f20 = MFMA32(*(const bf16x8*)(wp2),              hb0, z16);
  f20 = MFMA32(*(const bf16x8*)(wp2 + 64 * 8),     hb1, f20);
  f21 = MFMA32(*(const bf16x8*)(wp2 + 2 * 64 * 8), hb0, z16);
  f21 = MFMA32(*(const bf16x8*)(wp2 + 3 * 64 * 8), hb1, f21);

  // residual2 + LN2 + store
  float v1 = 0.f, v2 = 0.f;
  float va0[16], va1[16];
  #pragma unroll
  for (int r = 0; r < 16; ++r) {
    va0[r] = f20[r] + y0[r];
    va1[r] = f21[r] + y1[r];
    v1 += va0[r] + va1[r];
    v2 += va0[r] * va0[r] + va1[r] * va1[r];
  }
  v1 = redsum32(v1);
  v2 = redsum32(v2);
  const float mu2   = v1 * (1.f / 64.f);
  const float var2  = v2 * (1.f / 64.f) - mu2 * mu2;
  const float rstd2 = rsqrtf(var2 + 1e-5f);

  float* op = out + ((size_t)(b * NCTX + n)) * DH + 4 * hi;
  #pragma unroll
  for (int g = 0; g < 4; ++g) {
    f32x4 st0, st1;
    #pragma unroll
    for (int j = 0; j < 4; ++j) {
      st0[j] = (va0[4 * g + j] - mu2) * rstd2;
      st1[j] = (va1[4 * g + j] - mu2) * rstd2;
    }
    *(f32x4*)(op + 8 * g)      = st0;
    *(f32x4*)(op + 32 + 8 * g) = st1;
  }
#undef LOADK
#undef QK
}

// ---------------------------------------------------------------------------
extern "C" void kernel_launch(void* const* d_in, const int* in_sizes, int n_in,
                              void* d_out, int out_size, void* d_ws, size_t ws_size,
                              hipStream_t stream)
{
  const float* x   = (const float*)d_in[0];
  const float* wq  = (const float*)d_in[1];
  const float* wk  = (const float*)d_in[2];
  const float* wv  = (const float*)d_in[3];
  const float* w1  = (const float*)d_in[4];
  const float* w2  = (const float*)d_in[5];
  const float* kpm = (const float*)d_in[6];
  // d_in[7] = causal_mask: handled structurally (triu(k=1) == -1e9 additive)
  float* out = (float*)d_out;

  char* ws = (char*)d_ws;
  const size_t nelem = (size_t)ZB * NCTX * DH;     // 8388608
  __bf16* Qb   = (__bf16*)(ws);
  __bf16* Kb   = (__bf16*)(ws + nelem * 2);
  __bf16* Vt   = (__bf16*)(ws + nelem * 4);        // [Z][D][N]
  float*  kpmS = (float*)(ws + nelem * 6);         // ZB*NCTX f32
  __bf16* w1p  = (__bf16*)(ws + nelem * 6 + (size_t)ZB * NCTX * 4);
  __bf16* w2p  = w1p + 4 * 64 * 8;

  proj_kernel <<<1024, 256, 0, stream>>>(x, wq, wk, wv, w1, w2, kpm,
                                         Qb, Kb, Vt, kpmS, w1p, w2p);
  fused_kernel<<<ZB * 32, 128, 0, stream>>>(Qb, Kb, Vt, kpmS, x, w1p, w2p, out);
}